// Round 11
// baseline (286.568 us; speedup 1.0000x reference)
//
#include <hip/hip_runtime.h>
#include <stdint.h>
#include <stddef.h>

typedef unsigned short u16;
typedef __attribute__((ext_vector_type(8))) short  bf16x8;   // 8 bf16 = 4 VGPR (MFMA A/B frag)
typedef __attribute__((ext_vector_type(4))) unsigned short u16x4;
typedef __attribute__((ext_vector_type(4))) float  f32x4;

#define DEVI __device__ __forceinline__

DEVI float bf2f(u16 u){ union{uint32_t i; float f;} v; v.i = ((uint32_t)u)<<16; return v.f; }
DEVI u16 f2bf(float f){ union{float f; uint32_t i;} v; v.f=f; uint32_t r = v.i + 0x7fffu + ((v.i>>16)&1u); return (u16)(r>>16); }

DEVI void gload_lds16(const void* g, void* l){
  __builtin_amdgcn_global_load_lds((const __attribute__((address_space(1))) void*)g,
                                   (__attribute__((address_space(3))) void*)l, 16, 0, 0);
}

// ---------------- fused prep: x->bf16 cvt + Wqkv^T + Wproj^T (one launch) ----------------
__global__ __launch_bounds__(256) void k_prep(
    const float* __restrict__ x,     u16* __restrict__ xb,
    const float* __restrict__ Wqkv,  u16* __restrict__ WqkvT,
    const float* __restrict__ Wproj, u16* __restrict__ WprojT)
{
  __shared__ float tile[32][33];
  int bid = blockIdx.x;
  int tid = threadIdx.x;
  if (bid < 2048){                       // cvt x (8,388,608 f32)
    int i = (bid*256 + tid)*4;
    const int st = 2048*256*4;
    for (; i < 8388608; i += st){
      f32x4 v = *(const f32x4*)(x + i);
      u16x4 o;
      #pragma unroll
      for (int j=0;j<4;j++) o[j] = f2bf(v[j]);
      *(u16x4*)(xb + i) = o;
    }
    return;
  }
  const float* in; u16* out; int K, N, nb, kb;
  if (bid < 2048 + 12288){               // Wqkv [2048][6144] -> [6144][2048]
    int b2 = bid - 2048; in = Wqkv; out = WqkvT; K = 2048; N = 6144;
    nb = (b2 % 192)*32; kb = (b2 / 192)*32;
  } else {                               // Wproj [2048][2048] -> [2048][2048]
    int b3 = bid - 2048 - 12288; in = Wproj; out = WprojT; K = 2048; N = 2048;
    nb = (b3 % 64)*32; kb = (b3 / 64)*32;
  }
  int tx = tid & 31, ty = tid >> 5;
  #pragma unroll
  for (int i=0;i<32;i+=8)
    tile[ty+i][tx] = in[(size_t)(kb+ty+i)*N + nb+tx];
  __syncthreads();
  #pragma unroll
  for (int i=0;i<32;i+=8)
    out[(size_t)(nb+ty+i)*K + kb+tx] = f2bf(tile[tx][ty+i]);
}

// ============ 256x256 8-wave GEMM — m201-faithful quadrant pipeline ============
// A[M][K] bf16 @ Bt[N][K] bf16 (+bias f32). BK=64, 2 K-tiles/iter (even->buf0, odd->buf1).
// LDS 128 KiB: sA/sB[2 dbuf][2 half(128 rows)][128x64 bf16 = 16KB] — half = M/N-ROW half.
// Waves 2M x 4N; wave tile 128x64; acc[8][4] f32x4 = 128 VGPR.
// Per K-tile: 4 quadrant phases (mh,nh) = (0,0)(0,1)(1,1)(1,0); 16 MFMA each;
//   A regs live 2 phases, b0 lives ph1->ph4 (no LDS re-read) -> 24 ds_read_b128/tile.
// Phase: [ds_reads | stage 1 half (2 gload_lds) | (vmcnt@ph4/8) | barrier |
//         lgkmcnt(0) | 16 MFMA (setprio) | barrier].  Double barrier makes
//   stage-into-prev-phase-slab race-free (lgkm drain precedes BAR2).
// Stage slots: ph1:A1h0(Q) ph2:A1h1(Q) ph3:B0h0(P+2) ph4:B0h1(P+2)
//              ph5:A0h0(P+2) ph6:A0h1(P+2) ph7:B1h0(Q+2) ph8:B1h1(Q+2)
// vmcnt(4) at ph4+ph8 certifies the 4 halves read next (ledger simulated, incl.
//   prologue [6 halves, vmcnt(4)] and tail [no ph3-8 stages, ph4 drains to 0]).
// Slab swizzle [128r][64k]: byte(r,k16)=r*128+((k16^(r&7))<<4) — b128 reads
//   conflict-free; staged linearly via inverse-swizzled global source offsets.
#define STG(SLABP, GHALF) \
  gload_lds16((GHALF) + offG[0], (SLABP) + tid*8); \
  gload_lds16((GHALF) + offG[1], (SLABP) + 4096 + tid*8);

#define RD_A(BUF, MH) \
  { const char* sp_ = (const char*)&sA[BUF][wm][0]; \
    _Pragma("unroll") for (int f=0; f<4; f++) \
    _Pragma("unroll") for (int ks=0; ks<2; ks++){ \
      int r_ = (MH)*64 + f*16 + lr; \
      int k16_ = ks*4 + lg; \
      a[f*2+ks] = *(const bf16x8*)(sp_ + r_*128 + ((k16_ ^ (r_&7))<<4)); } }

#define RD_B(BUF, NH, BREG) \
  { const char* sp_ = (const char*)&sB[BUF][wn>>1][0]; \
    _Pragma("unroll") for (int g=0; g<2; g++) \
    _Pragma("unroll") for (int ks=0; ks<2; ks++){ \
      int r_ = (wn&1)*64 + (NH)*32 + g*16 + lr; \
      int k16_ = ks*4 + lg; \
      BREG[g*2+ks] = *(const bf16x8*)(sp_ + r_*128 + ((k16_ ^ (r_&7))<<4)); } }

#define MMQ(MH, NH, BREG) \
  __builtin_amdgcn_s_setprio(1); \
  { _Pragma("unroll") for (int f=0; f<4; f++) \
    _Pragma("unroll") for (int g=0; g<2; g++) \
    _Pragma("unroll") for (int ks=0; ks<2; ks++) \
      acc[(MH)*4+f][(NH)*2+g] = __builtin_amdgcn_mfma_f32_16x16x32_bf16( \
        a[f*2+ks], BREG[g*2+ks], acc[(MH)*4+f][(NH)*2+g], 0,0,0); } \
  __builtin_amdgcn_s_setprio(0);

#define BARX \
  __builtin_amdgcn_s_barrier(); \
  asm volatile("s_waitcnt lgkmcnt(0)" ::: "memory"); \
  __builtin_amdgcn_sched_barrier(0);

#define BAR2 \
  __builtin_amdgcn_s_barrier(); \
  __builtin_amdgcn_sched_barrier(0);

#define WAITV(N) asm volatile("s_waitcnt vmcnt(" #N ")" ::: "memory");
#define ORDER_FENCE __builtin_amdgcn_sched_barrier(0); asm volatile("" ::: "memory");

template<bool OUT_BF16>
__global__ __launch_bounds__(512, 1) void k_gemm256m(
    const u16* __restrict__ A, const u16* __restrict__ Bt,
    const float* __restrict__ bias, void* __restrict__ Cout,
    int M, int N, int K, int nbnx)   // nbnx = (N/256)/8 = bn-panels per XCD
{
  __shared__ __attribute__((aligned(16))) u16 sA[2][2][8192];
  __shared__ __attribute__((aligned(16))) u16 sB[2][2][8192];
  int orig = blockIdx.x;
  int xcd = orig & 7;
  int idx = orig >> 3;
  int bn  = xcd*nbnx + idx % nbnx;     // L2-resident B-panel set per XCD
  int bm  = idx / nbnx;
  const int tid = threadIdx.x;
  const int wid = tid>>6, l = tid&63;
  const int lr = l&15, lg = l>>4;
  const int wm = wid>>2, wn = wid&3;   // 2M x 4N waves, wave tile 128x64

  uint32_t offG[2];
  #pragma unroll
  for (int j=0;j<2;j++){
    int s = tid + 512*j;
    int r = s>>3, kg = (s&7)^(r&7);
    offG[j] = (uint32_t)(r*K + kg*8);
  }
  const u16* Abase = A + (size_t)(bm*256)*K;
  const u16* Bbase = Bt + (size_t)(bn*256)*K;
  const size_t HK = (size_t)128*K;     // row-half stride

  f32x4 acc[8][4] = {};
  bf16x8 a[8], b0[4], b1[4];
  const int NI = K>>7;                 // 2 K-tiles (of 64) per iter; K % 128 == 0

  // prologue: tile0 all 4 halves + tile1 B halves (12 loads); retire first 8
  STG(&sA[0][0][0], Abase);
  STG(&sA[0][1][0], Abase + HK);
  ORDER_FENCE;
  STG(&sB[0][0][0], Bbase);
  STG(&sB[0][1][0], Bbase + HK);
  ORDER_FENCE;
  STG(&sB[1][0][0], Bbase + 64);
  STG(&sB[1][1][0], Bbase + HK + 64);
  WAITV(4);
  __builtin_amdgcn_s_barrier();
  __builtin_amdgcn_sched_barrier(0);

  for (int t=0; t<NI; ++t){
    const bool full = (t+1 < NI);
    const u16* Aq = Abase + (2*t+1)*64;   // tile Q (this iter, buf1)
    const u16* An = Abase + (2*t+2)*64;   // tile P+2 (next, buf0)
    const u16* Bn = Bbase + (2*t+2)*64;
    // ph1: read A(P,mh0)+B(P,nh0); stage A1h0(Q)
    RD_A(0,0); RD_B(0,0,b0);
    STG(&sA[1][0][0], Aq);
    BARX; MMQ(0,0,b0); BAR2;
    // ph2: read B(P,nh1); stage A1h1(Q)
    RD_B(0,1,b1);
    STG(&sA[1][1][0], Aq + HK);
    BARX; MMQ(0,1,b1); BAR2;
    // ph3: read A(P,mh1); stage B0h0(P+2)
    RD_A(0,1);
    if (full){ STG(&sB[0][0][0], Bn); }
    BARX; MMQ(1,1,b1); BAR2;
    // ph4: no reads; stage B0h1(P+2); vmcnt
    if (full){ STG(&sB[0][1][0], Bn + HK); WAITV(4); } else { WAITV(0); }
    BARX; MMQ(1,0,b0); BAR2;
    // ph5: read A(Q,mh0)+B(Q,nh0); stage A0h0(P+2)
    RD_A(1,0); RD_B(1,0,b0);
    if (full){ STG(&sA[0][0][0], An); }
    BARX; MMQ(0,0,b0); BAR2;
    // ph6: read B(Q,nh1); stage A0h1(P+2)
    RD_B(1,1,b1);
    if (full){ STG(&sA[0][1][0], An + HK); }
    BARX; MMQ(0,1,b1); BAR2;
    // ph7: read A(Q,mh1); stage B1h0(Q+2)
    RD_A(1,1);
    if (full){ STG(&sB[1][0][0], Bn + 64); }
    BARX; MMQ(1,1,b1); BAR2;
    // ph8: no reads; stage B1h1(Q+2); vmcnt
    if (full){ STG(&sB[1][1][0], Bn + HK + 64); WAITV(4); }
    BARX; MMQ(1,0,b0); BAR2;
  }

  // epilogue
  #pragma unroll
  for (int nf=0; nf<4; nf++){
    int col = bn*256 + wn*64 + (nf>>1)*32 + (nf&1)*16 + lr;
    float bv = bias[col];
    #pragma unroll
    for (int mf=0; mf<8; mf++){
      int rbase = bm*256 + wm*128 + (mf>>2)*64 + (mf&3)*16 + lg*4;
      #pragma unroll
      for (int j=0; j<4; j++){
        float v = acc[mf][nf][j] + bv;   // C/D map: col=lane&15, row=(lane>>4)*4+reg
        if (OUT_BF16) ((u16*)Cout)[(size_t)(rbase+j)*N + col] = f2bf(v);
        else          ((float*)Cout)[(size_t)(rbase+j)*N + col] = v;
      }
    }
  }
}

// ---------------- GEMM2: 128x128 2-phase (proven) + XCD-local bn ----------------
template<bool OUT_BF16>
__global__ __launch_bounds__(256) void k_gemm_bt(
    const u16* __restrict__ A, const u16* __restrict__ Bt,
    const float* __restrict__ bias, void* __restrict__ Cout,
    int M, int N, int K, int nbnx)   // nbnx = (N/128)/8
{
  __shared__ __attribute__((aligned(16))) u16 sA2[128*64];
  __shared__ __attribute__((aligned(16))) u16 sB2[128*64];
  int orig = blockIdx.x;
  int xcd = orig & 7;
  int idx = orig >> 3;
  int bn  = xcd*nbnx + idx % nbnx;
  int bm  = idx / nbnx;
  const int tid = threadIdx.x;
  const int w = tid>>6, l = tid&63;
  const int lr = l&15, lg = l>>4;
  const int wr = (w>>1)*64, wc = (w&1)*64;
  const size_t rowA = (size_t)bm*128;
  const size_t rowB = (size_t)bn*128;
  f32x4 acc[4][4] = {};
  for (int k0=0; k0<K; k0+=64){
    #pragma unroll
    for (int it=0; it<4; ++it){
      int c = it*256 + tid;
      int r = c>>3, k8 = (c&7) ^ (r&7);
      gload_lds16(A + (rowA+r)*K + k0 + k8*8, &sA2[c*8]);
    }
    #pragma unroll
    for (int it=0; it<4; ++it){
      int c = it*256 + tid;
      int r = c>>3, k8 = (c&7) ^ (r&7);
      gload_lds16(Bt + (rowB+r)*K + k0 + k8*8, &sB2[c*8]);
    }
    __syncthreads();
    #pragma unroll
    for (int ks=0; ks<2; ++ks){
      bf16x8 af[4], bfr[4];
      #pragma unroll
      for (int m=0;m<4;m++){
        int row = wr + m*16 + lr, k = ks*32 + lg*8;
        int byt = ((row<<7) + (k<<1)) ^ ((row&7)<<4);
        af[m] = *(const bf16x8*)((const char*)sA2 + byt);
      }
      #pragma unroll
      for (int n=0;n<4;n++){
        int row = wc + n*16 + lr, k = ks*32 + lg*8;
        int byt = ((row<<7) + (k<<1)) ^ ((row&7)<<4);
        bfr[n] = *(const bf16x8*)((const char*)sB2 + byt);
      }
      #pragma unroll
      for (int m=0;m<4;m++)
        #pragma unroll
        for (int n=0;n<4;n++)
          acc[m][n] = __builtin_amdgcn_mfma_f32_16x16x32_bf16(af[m], bfr[n], acc[m][n], 0,0,0);
    }
    __syncthreads();
  }
  #pragma unroll
  for (int n=0;n<4;n++){
    int col = bn*128 + wc + n*16 + lr;
    float bv = bias[col];
    #pragma unroll
    for (int m=0;m<4;m++){
      #pragma unroll
      for (int j=0;j<4;j++){
        int row = bm*128 + wr + m*16 + lg*4 + j;
        float v = acc[m][n][j] + bv;
        if (OUT_BF16) ((u16*)Cout)[(size_t)row*N + col] = f2bf(v);
        else          ((float*)Cout)[(size_t)row*N + col] = v;
      }
    }
  }
}

// ---------------- pointwise: RMSNorm + RoPE(q,k), value mix, V-transpose, v1 passthrough ----------------
DEVI void unpack16(const u16* p, float* f){
  bf16x8 a = *(const bf16x8*)p, b = *(const bf16x8*)(p+8);
  #pragma unroll
  for (int i=0;i<8;i++){ f[i]=bf2f((u16)a[i]); f[8+i]=bf2f((u16)b[i]); }
}

__global__ __launch_bounds__(256) void k_qkv_post(
    const u16*  __restrict__ qkv,   // [4096][6144] bf16
    const float* __restrict__ v1,   // [B][T][16][128] f32
    const float* __restrict__ lambp,
    u16* __restrict__ qn,           // [4096][2048]
    u16* __restrict__ kn,           // [4096][2048]
    u16* __restrict__ vT,           // [B][16][128][1024]
    float* __restrict__ v1out)      // passthrough copy of v1 (output 1)
{
  __shared__ float cosv[64], sinv[64];
  __shared__ __attribute__((aligned(16))) u16 sv[64][136];  // value tile [t][d], padded
  int bid = blockIdx.x;
  int tb = bid & 15, h = (bid>>4)&15, b = bid>>8;
  int tid = threadIdx.x;
  if (tid < 64){
    // freqs[h][j] = h * 10000^(-j/64);  log2(10000)/64 = 0.20762050593045951
    float ang = (float)h * exp2f(-(float)tid * 0.2076205059304595f);
    cosv[tid] = cosf(ang);
    sinv[tid] = sinf(ang);
  }
  float lamb = lambp[0];
  int row = tid>>2, p = tid&3;
  int t = tb*64 + row;
  size_t base = ((size_t)(b*1024 + t))*6144 + (size_t)h*128;
  __syncthreads();

  // q and k: RMSNorm then RoPE (RoPE is linear -> scale commutes)
  #pragma unroll
  for (int qc=0; qc<2; ++qc){
    const u16* src = qkv + base + qc*2048;
    u16* dst = (qc==0 ? qn : kn) + ((size_t)(b*1024+t))*2048 + h*128;
    int j0 = p*16;
    float x1[16], x2[16];
    unpack16(src + j0, x1);
    unpack16(src + 64 + j0, x2);
    float ss = 0.f;
    #pragma unroll
    for (int i=0;i<16;i++) ss += x1[i]*x1[i] + x2[i]*x2[i];
    ss += __shfl_xor(ss, 1);
    ss += __shfl_xor(ss, 2);
    float rn = rsqrtf(ss*(1.0f/128.0f) + 1e-6f);
    bf16x8 o1a,o1b,o2a,o2b;
    #pragma unroll
    for (int i=0;i<16;i++){
      float c = cosv[j0+i], s = sinv[j0+i];
      u16 a = f2bf(( x1[i]*c + x2[i]*s)*rn);
      u16 bq= f2bf((-x1[i]*s + x2[i]*c)*rn);
      if (i<8){ o1a[i]=(short)a; o2a[i]=(short)bq; } else { o1b[i-8]=(short)a; o2b[i-8]=(short)bq; }
    }
    *(bf16x8*)(dst + j0)      = o1a;
    *(bf16x8*)(dst + j0 + 8)  = o1b;
    *(bf16x8*)(dst + 64 + j0)     = o2a;
    *(bf16x8*)(dst + 64 + j0 + 8) = o2b;
  }

  // value = (1-lamb)*v + lamb*v1  -> LDS tile (for transpose); also v1 passthrough
  {
    const u16* srcv = qkv + base + 4096;
    size_t v1off = (((size_t)(b*1024+t))*16 + h)*128;
    const float* src1 = v1 + v1off;
    float* dst1 = v1out + v1off;
    int d0 = p*32;
    #pragma unroll
    for (int c8=0;c8<4;c8++){
      bf16x8 vv = *(const bf16x8*)(srcv + d0 + c8*8);
      f32x4 a0 = *(const f32x4*)(src1 + d0 + c8*8);
      f32x4 a1 = *(const f32x4*)(src1 + d0 + c8*8 + 4);
      *(f32x4*)(dst1 + d0 + c8*8) = a0;
      *(f32x4*)(dst1 + d0 + c8*8 + 4) = a1;
      bf16x8 o;
      #pragma unroll
      for (int i=0;i<8;i++){
        float x1v = (i<4)? a0[i] : a1[i-4];
        o[i] = (short)f2bf((1.0f-lamb)*bf2f((u16)vv[i]) + lamb*x1v);
      }
      *(bf16x8*)(&sv[row][d0 + c8*8]) = o;
    }
  }
  __syncthreads();
  // write vT[b][h][d][t]
  {
    int d = tid>>1, tc = (tid&1)*32;
    u16 tmp[32];
    #pragma unroll
    for (int i=0;i<32;i++) tmp[i] = sv[tc+i][d];
    u16* dst = vT + (((size_t)(b*16+h))*128 + d)*1024 + tb*64 + tc;
    #pragma unroll
    for (int c8=0;c8<4;c8++){
      bf16x8 o;
      #pragma unroll
      for (int i=0;i<8;i++) o[i]=(short)tmp[c8*8+i];
      *(bf16x8*)(dst + c8*8) = o;
    }
  }
}

// ---------------- flash attention (causal), bf16 MFMA, pipelined ----------------
__global__ __launch_bounds__(256) void k_attn(
    const u16* __restrict__ Q,   // [4096][2048] (b,t,h,d)
    const u16* __restrict__ Kn,  // same
    const u16* __restrict__ Vt,  // [B][16][128][1024]
    u16* __restrict__ O)         // [4096][2048]
{
  __shared__ __attribute__((aligned(16))) u16 sK[2][64*128];
  __shared__ __attribute__((aligned(16))) u16 sV[2][128*64];
  __shared__ __attribute__((aligned(16))) u16 sP[4][16*64];
  int bid = blockIdx.x;
  int qi = 15 - (bid>>6);          // heavy q-tiles dispatch first (tail kill)
  int bh = bid & 63;
  int h = bh & 15, b = bh >> 4;
  int tid = threadIdx.x, w = tid>>6, l = tid&63, lr = l&15, lg = l>>4;
  int qrow = qi*64 + w*16;
  bf16x8 aq[4];
  {
    const u16* qp = Q + ((size_t)(b*1024 + qrow + lr))*2048 + h*128 + lg*8;
    #pragma unroll
    for (int ks=0; ks<4; ++ks) aq[ks] = *(const bf16x8*)(qp + ks*32);
  }
  f32x4 accO[8] = {};
  float mrun[4], srun[4];
  #pragma unroll
  for (int j=0;j<4;j++){ mrun[j] = -INFINITY; srun[j]=0.f; }
  const float scale = 0.08838834764831845f;   // 1/sqrt(128)
  const size_t kbase = (size_t)(b*1024)*2048 + (size_t)h*128;
  const u16* vbase = Vt + ((size_t)(b*16+h))*128*1024;

  auto STAGE = [&](int kt, int buf){
    #pragma unroll
    for (int it=0; it<4; ++it){           // K tile: [64 key][128 d], swizzled source
      int c = it*256+tid;
      int key = c>>4, d16 = (c&15)^(key&7);
      gload_lds16(Kn + kbase + (size_t)(kt*64+key)*2048 + d16*8, &sK[buf][c*8]);
    }
    #pragma unroll
    for (int it=0; it<4; ++it){           // V tile: [128 d][64 key]
      int c = it*256+tid;
      int d = c>>3, k8 = (c&7)^(d&7);
      gload_lds16(vbase + (size_t)d*1024 + kt*64 + k8*8, &sV[buf][c*8]);
    }
  };

  STAGE(0, 0);
  int cur = 0;
  for (int kt=0; kt<=qi; ++kt){
    if (kt < qi){
      STAGE(kt+1, cur^1);                            // prefetch next tile
      asm volatile("s_waitcnt vmcnt(8)" ::: "memory"); // wait current tile only
    } else {
      asm volatile("s_waitcnt vmcnt(0)" ::: "memory");
    }
    __builtin_amdgcn_s_barrier();
    __builtin_amdgcn_sched_barrier(0);
    const char* kb = (const char*)sK[cur];
    const char* vb = (const char*)sV[cur];

    f32x4 accS[4] = {};
    __builtin_amdgcn_s_setprio(1);
    #pragma unroll
    for (int ks=0; ks<4; ++ks){
      #pragma unroll
      for (int n=0;n<4;n++){
        int key = n*16+lr, k = ks*32+lg*8;
        int byt = ((key<<8) + (k<<1)) ^ ((key&7)<<4);
        bf16x8 bk = *(const bf16x8*)(kb + byt);
        accS[n] = __builtin_amdgcn_mfma_f32_16x16x32_bf16(aq[ks], bk, accS[n], 0,0,0);
      }
    }
    __builtin_amdgcn_s_setprio(0);
    bool diag = (kt == qi);
    float pj[4][4];
    #pragma unroll
    for (int j=0;j<4;j++){
      int qg = qrow + lg*4 + j;
      float mx = -INFINITY;
      #pragma unroll
      for (int n=0;n<4;n++){
        float s = accS[n][j]*scale;
        if (diag && (kt*64 + n*16 + lr) > qg) s = -1e30f;
        pj[n][j] = s;
        mx = fmaxf(mx, s);
      }
      #pragma unroll
      for (int off=1; off<16; off<<=1) mx = fmaxf(mx, __shfl_xor(mx, off));
      float mnew = fmaxf(mrun[j], mx);
      float fac = __expf(mrun[j] - mnew);
      float ps = 0.f;
      #pragma unroll
      for (int n=0;n<4;n++){ float e = __expf(pj[n][j]-mnew); pj[n][j]=e; ps += e; }
      #pragma unroll
      for (int off=1; off<16; off<<=1) ps += __shfl_xor(ps, off);
      srun[j] = srun[j]*fac + ps;
      mrun[j] = mnew;
      #pragma unroll
      for (int n=0;n<8;n++) accO[n][j] *= fac;
    }
    // P -> wave-private swizzled LDS (A-operand layout for PV)
    #pragma unroll
    for (int n=0;n<4;n++)
      #pragma unroll
      for (int j=0;j<4;j++){
        int q = lg*4+j, key = n*16+lr;
        int byt = ((q<<7) + (key<<1)) ^ ((q&7)<<4);
        *(u16*)((char*)sP[w] + byt) = f2bf(pj[n][j]);
      }
    bf16x8 pA[2];
    #pragma unroll
    for (int ks=0; ks<2; ++ks){
      int k = ks*32 + lg*8;
      int byt = ((lr<<7) + (k<<1)) ^ ((lr&7)<<4);
      pA[ks] = *(const bf16x8*)((const char*)sP[w] + byt);
    }
    __builtin_amdgcn_s_setprio(1);
    #pragma unroll
    for (int ks=0; ks<2; ++ks)
      #pragma unroll
      for (int n=0;n<8;n++){
        int d = n*16+lr, k = ks*32+lg*8;
        int byt = ((d<<7) + (k<<1)) ^ ((d&7)<<4);
        bf16x8 bv = *(const bf16x8*)(vb + byt);
        accO[n] = __builtin_amdgcn_mfma_f32_16x16x32_bf16(pA[ks], bv, accO[n], 0,0,0);
      }
    __builtin_amdgcn_s_setprio(0);
    __builtin_amdgcn_s_barrier();   // protect buf[cur^1]-compute vs next STAGE overwrite
    cur ^= 1;
  }
  #pragma unroll
  for (int j=0;j<4;j++){
    float inv = 1.0f / srun[j];
    int row = qrow + lg*4 + j;
    u16* op = O + ((size_t)(b*1024+row))*2048 + h*128;
    #pragma unroll
    for (int n=0;n<8;n++)
      op[n*16+lr] = f2bf(accO[n][j]*inv);
  }
}

// ---------------- launch ----------------
extern "C" void kernel_launch(void* const* d_in, const int* in_sizes, int n_in,
                              void* d_out, int out_size, void* d_ws, size_t ws_size,
                              hipStream_t stream)
{
  const float* x     = (const float*)d_in[0];
  const float* v1    = (const float*)d_in[1];
  const float* Wqkv  = (const float*)d_in[2];
  const float* bqkv  = (const float*)d_in[3];
  const float* Wproj = (const float*)d_in[4];
  const float* bproj = (const float*)d_in[5];
  const float* lamb  = (const float*)d_in[6];

  char* ws = (char*)d_ws;
  u16* qkv_b  = (u16*)(ws);                // 50,331,648 B  [4096][6144]
  u16* WqkvT  = (u16*)(ws +  50331648);    // 25,165,824 B  [6144][2048]
  u16* WprojT = (u16*)(ws +  75497472);    //  8,388,608 B  [2048][2048]
  u16* xb     = (u16*)(ws +  83886080);    // 16,777,216 B  [4096][2048] (reused as vT)
  u16* vT     = xb;                        // alias: xb dead after GEMM1
  u16* qn     = (u16*)(ws + 100663296);    // 16,777,216 B
  u16* kn     = (u16*)(ws + 117440512);    // 16,777,216 B   (total 128 MiB)
  u16* attn_b = qkv_b;                     // alias: qkv dead after pointwise

  float* out = (float*)d_out;

  hipLaunchKernelGGL(k_prep, dim3(2048+12288+4096), dim3(256), 0, stream,
                     x, xb, Wqkv, WqkvT, Wproj, WprojT);
  hipLaunchKernelGGL((k_gemm256m<true>),  dim3(384), dim3(512), 0, stream, xb, WqkvT, bqkv, (void*)qkv_b, 4096, 6144, 2048, 3);
  hipLaunchKernelGGL(k_qkv_post, dim3(1024), dim3(256), 0, stream, qkv_b, v1, lamb, qn, kn, vT, out + 8388608);
  hipLaunchKernelGGL(k_attn, dim3(1024), dim3(256), 0, stream, qn, kn, vT, attn_b);
  hipLaunchKernelGGL((k_gemm_bt<false>), dim3(512), dim3(256), 0, stream, attn_b, WprojT, bproj, (void*)out, 4096, 2048, 2048, 2);
}